// Round 3
// baseline (191.534 us; speedup 1.0000x reference)
//
#include <hip/hip_runtime.h>
#include <math.h>

#define S_LEN 4096
#define B_SZ  64
#define D_SZ  64
#define N_SZ  128
#define L_SZ  2
#define NSIG  32000
#define CH    8
#define NCHUNK (S_LEN / CH)   // 512

// f32-rounded constants matching jnp.float32(...)
#define PHI_F     1.6180339887498949f
#define TWO_PI_F  6.2831853071795862f
#define INV_PI_F  0.31830988618379067f
#define SQ2_I2PI  0.22507907903927651f   // sqrt(2)/(2*pi)

// ---------------------------------------------------------------------------
// Pre-pass: transform emb table so the scan's inner loop is 1 load + 1 add +
// fma + v_sin.  embT[v*64+d] = ( sqrt2/(2pi*(1+|w|)),  b/pi ).
// ---------------------------------------------------------------------------
__global__ __launch_bounds__(256) void transform_kernel(
    const float* __restrict__ emb, float2* __restrict__ embT)
{
    int e = blockIdx.x * 256 + threadIdx.x;   // [0, 32000*64)
    int v = e >> 6, d = e & 63;
    float w = emb[(v << 7) + d];
    float b = emb[(v << 7) + 64 + d];
    embT[e] = make_float2(SQ2_I2PI * __builtin_amdgcn_rcpf(1.0f + fabsf(w)),
                          b * INV_PI_F);
}

// ---------------------------------------------------------------------------
// Phase 1: the sequential scan.  grid = B (64 blocks), block = D (64 lanes).
// Identity: hr' = cos(psi), hi' = sin(psi), psi = (hr+hi)/lam + 2(b+tau).
// Track u = (hr+hi)/sqrt2:  q = fma(u, sqrt2/(2pi lam), (b+tau)/pi + 1/8);
//                           u = sin(2pi q).
// Dependent chain per step: fma -> v_sin.  8-slot register ring prefetches
// 7 chunks (56 steps, 56 outstanding loads) ahead.
// __launch_bounds__(64, 1): 1 wave/EU -> full 512-VGPR budget so the ring
// stays in registers and loads are issued at full depth (round-2 fix: the
// default budget capped us at 100 VGPRs and collapsed the pipeline).
// ---------------------------------------------------------------------------
template<bool XF>
__global__ __launch_bounds__(64, 1) void scan_kernel(
    const int*    __restrict__ ids,
    const float*  __restrict__ embR,    // raw emb        (used when !XF)
    const float2* __restrict__ embT,    // transformed    (used when XF)
    float2*       __restrict__ xf)      // [b][d] final (hr,hi)
{
    __shared__ int   s_ids[S_LEN];      // token id << 6 (pre-scaled)
    __shared__ float s_t2[S_LEN];       // tau/pi + 0.125

    const int b = blockIdx.x;
    const int d = threadIdx.x;

    for (int i = d; i < S_LEN; i += 64) {
        s_ids[i] = ids[b * S_LEN + i] << 6;
        s_t2[i]  = fmodf((float)i * PHI_F, TWO_PI_F) * INV_PI_F + 0.125f;
    }
    __syncthreads();

    float2 q0[CH], q1[CH], q2[CH], q3[CH], q4[CH], q5[CH], q6[CH], q7[CH];
    float  u = 0.0f, qang = 0.0f;

#define CLMP(X) ((X) < NCHUNK ? (X) : 0)

#define ISSUE(BUF, CHUNK) do {                                              \
    int base_ = (CHUNK) * CH;                                               \
    _Pragma("unroll")                                                       \
    for (int j = 0; j < CH; ++j) {                                          \
        int i64_ = s_ids[base_ + j];                                        \
        if constexpr (XF) {                                                 \
            BUF[j] = embT[i64_ + d];                                        \
        } else {                                                            \
            BUF[j].x = embR[(i64_ << 1) + d];                               \
            BUF[j].y = embR[(i64_ << 1) + 64 + d];                          \
        }                                                                   \
    }                                                                       \
} while (0)

#define CHAIN(BUF, CHUNK) do {                                              \
    int base_ = (CHUNK) * CH;                                               \
    _Pragma("unroll")                                                       \
    for (int j = 0; j < CH; ++j) {                                          \
        float t2_ = s_t2[base_ + j];                                        \
        float A_, C_;                                                       \
        if constexpr (XF) {                                                 \
            A_ = BUF[j].x;                                                  \
            C_ = BUF[j].y + t2_;                                            \
        } else {                                                            \
            A_ = SQ2_I2PI * __builtin_amdgcn_rcpf(1.0f + fabsf(BUF[j].x));  \
            C_ = fmaf(BUF[j].y, INV_PI_F, t2_);                             \
        }                                                                   \
        qang = fmaf(u, A_, C_);                                             \
        u    = __builtin_amdgcn_sinf(qang);                                 \
    }                                                                       \
} while (0)

    // prologue: chunks 0..6 into slots 0..6
    ISSUE(q0, 0); ISSUE(q1, 1); ISSUE(q2, 2); ISSUE(q3, 3);
    ISSUE(q4, 4); ISSUE(q5, 5); ISSUE(q6, 6);

    for (int c = 0; c < NCHUNK; c += 8) {
        ISSUE(q7, CLMP(c + 7));  CHAIN(q0, c + 0);
        ISSUE(q0, CLMP(c + 8));  CHAIN(q1, c + 1);
        ISSUE(q1, CLMP(c + 9));  CHAIN(q2, c + 2);
        ISSUE(q2, CLMP(c + 10)); CHAIN(q3, c + 3);
        ISSUE(q3, CLMP(c + 11)); CHAIN(q4, c + 4);
        ISSUE(q4, CLMP(c + 12)); CHAIN(q5, c + 5);
        ISSUE(q5, CLMP(c + 13)); CHAIN(q6, c + 6);
        ISSUE(q6, CLMP(c + 14)); CHAIN(q7, c + 7);
    }

    // final h: qang holds the last psi/(2pi) + 1/8
    float pr = qang - 0.125f;
    float hr = __builtin_amdgcn_cosf(pr);
    float hi = __builtin_amdgcn_sinf(pr);
    xf[b * 64 + d] = make_float2(hr, hi);

#undef ISSUE
#undef CHAIN
#undef CLMP
}

// ---------------------------------------------------------------------------
// Phase 2: the two resonant layers at t_last = (S-1)*phi.
// grid = B (64 blocks), block = N (128 threads).
// ---------------------------------------------------------------------------
__global__ __launch_bounds__(128) void layers_kernel(
    const float2* __restrict__ xf,       // [b][d]
    const float*  __restrict__ win_r,    // [L][D][N]
    const float*  __restrict__ win_i,
    const float*  __restrict__ wout_r,   // [L][N][D]
    const float*  __restrict__ wout_i,
    const float*  __restrict__ lw,       // [L][N]
    const float*  __restrict__ lb,
    float2*       __restrict__ xft)      // [d][b] for the projection kernel
{
    const int b = blockIdx.x;
    const int n = threadIdx.x;

    __shared__ float s_xr[D_SZ], s_xi[D_SZ];
    __shared__ float s_vr[N_SZ], s_vi[N_SZ];

    if (n < D_SZ) {
        float2 v = xf[b * D_SZ + n];
        s_xr[n] = v.x;
        s_xi[n] = v.y;
    }
    __syncthreads();

    const float t_last = (float)(4095.0 * 1.618033988749895);
    const float t_wrap = fmodf(t_last, TWO_PI_F);

    for (int l = 0; l < L_SZ; ++l) {
        float ur = 0.0f, ui = 0.0f;
        const float* wr = win_r + l * D_SZ * N_SZ;
        const float* wi = win_i + l * D_SZ * N_SZ;
        for (int dd = 0; dd < D_SZ; ++dd) {
            float xr = s_xr[dd], xi = s_xi[dd];
            float ar = wr[dd * N_SZ + n], ai = wi[dd * N_SZ + n];
            ur = fmaf(xr, ar, fmaf(-xi, ai, ur));
            ui = fmaf(xr, ai, fmaf( xi, ar, ui));
        }
        float lam = 1.0f + fabsf(lw[l * N_SZ + n]);
        float th  = t_wrap / lam + lb[l * N_SZ + n];
        float sn  = sinf(th), cs = cosf(th);
        float vr  = ur * cs - ui * sn;
        float vi  = ur * sn + ui * cs;
        vr = vr / (1.0f + expf(-vr));
        vi = vi / (1.0f + expf(-vi));
        s_vr[n] = vr;
        s_vi[n] = vi;
        __syncthreads();

        float yr = 0.0f, yi = 0.0f;
        if (n < D_SZ) {
            const float* orp = wout_r + l * N_SZ * D_SZ;
            const float* oip = wout_i + l * N_SZ * D_SZ;
            for (int j = 0; j < N_SZ; ++j) {
                float vr2 = s_vr[j], vi2 = s_vi[j];
                float br = orp[j * D_SZ + n], bi = oip[j * D_SZ + n];
                yr = fmaf(vr2, br, fmaf(-vi2, bi, yr));
                yi = fmaf(vr2, bi, fmaf( vi2, br, yi));
            }
        }
        __syncthreads();
        if (n < D_SZ) {
            s_xr[n] = yr;
            s_xi[n] = yi;
        }
        __syncthreads();
    }

    if (n < D_SZ) {
        xft[n * B_SZ + b] = make_float2(s_xr[n], s_xi[n]);
    }
}

// ---------------------------------------------------------------------------
// Phase 3: out[b][v] = xr[b]@(wr+wi)[:,v] + xi[b]@(wr-wi)[:,v].
// ---------------------------------------------------------------------------
#define VCH 16
__global__ __launch_bounds__(64) void proj_kernel(
    const float2* __restrict__ xft,    // [d][b]
    const float*  __restrict__ owr,    // [D][NSIG]
    const float*  __restrict__ owi,
    float*        __restrict__ out)    // [B][NSIG]
{
    const int v0   = blockIdx.x * VCH;
    const int lane = threadIdx.x;      // = b

    float acc[VCH];
    #pragma unroll
    for (int k = 0; k < VCH; ++k) acc[k] = 0.0f;

    for (int dd = 0; dd < D_SZ; ++dd) {
        float2 x = xft[dd * B_SZ + lane];
        #pragma unroll
        for (int k = 0; k < VCH; ++k) {
            float a = owr[dd * NSIG + v0 + k];
            float c = owi[dd * NSIG + v0 + k];
            acc[k] = fmaf(x.x, a + c, fmaf(x.y, a - c, acc[k]));
        }
    }

    float4* o4 = (float4*)(out + (size_t)lane * NSIG + v0);
    #pragma unroll
    for (int k = 0; k < VCH / 4; ++k) {
        o4[k] = make_float4(acc[4 * k], acc[4 * k + 1],
                            acc[4 * k + 2], acc[4 * k + 3]);
    }
}

// ---------------------------------------------------------------------------
extern "C" void kernel_launch(void* const* d_in, const int* in_sizes, int n_in,
                              void* d_out, int out_size, void* d_ws, size_t ws_size,
                              hipStream_t stream)
{
    const int*   ids    = (const int*)  d_in[0];
    const float* emb    = (const float*)d_in[1];
    const float* win_r  = (const float*)d_in[2];
    const float* win_i  = (const float*)d_in[3];
    const float* wout_r = (const float*)d_in[4];
    const float* wout_i = (const float*)d_in[5];
    const float* lw     = (const float*)d_in[6];
    const float* lb     = (const float*)d_in[7];
    const float* owr    = (const float*)d_in[8];
    const float* owi    = (const float*)d_in[9];
    float*       out    = (float*)d_out;

    float2* xf   = (float2*)d_ws;                        // 32 KB
    float2* xft  = (float2*)((char*)d_ws + 32 * 1024);   // 32 KB
    float2* embT = (float2*)((char*)d_ws + 64 * 1024);   // 16.4 MB

    const size_t need = 64 * 1024 + (size_t)NSIG * 64 * sizeof(float2);
    if (ws_size >= need) {
        transform_kernel<<<NSIG * 64 / 256, 256, 0, stream>>>(emb, embT);
        scan_kernel<true><<<B_SZ, 64, 0, stream>>>(ids, emb, embT, xf);
    } else {
        scan_kernel<false><<<B_SZ, 64, 0, stream>>>(ids, emb, (const float2*)emb, xf);
    }
    layers_kernel<<<B_SZ, 128, 0, stream>>>(xf, win_r, win_i, wout_r, wout_i,
                                            lw, lb, xft);
    proj_kernel<<<NSIG / VCH, 64, 0, stream>>>(xft, owr, owi, out);
}

// Round 5
// 116.916 us; speedup vs baseline: 1.6382x; 1.6382x over previous
//
#include <hip/hip_runtime.h>
#include <math.h>

#define S_LEN 4096
#define B_SZ  64
#define D_SZ  64
#define N_SZ  128
#define L_SZ  2
#define NSIG  32000

#define TILE   128
#define NT     (S_LEN / TILE)     // 32
#define GRP    16                 // consumer prefetch group
#define PWAVES 4
#define PSTEPS (TILE / PWAVES)    // 32 steps per producer wave per tile

// f32-rounded constants matching jnp.float32(...)
#define PHI_F     1.6180339887498949f
#define TWO_PI_F  6.2831853071795862f
#define INV_PI_F  0.31830988618379067f
#define SQ2_I2PI  0.22507907903927651f   // sqrt(2) / (2*pi)

// ---------------------------------------------------------------------------
// Pre-pass (identical to the round-2/3 PASSING version):
//   embT[v*64+d] = ( A = sqrt2/(2pi*(1+|w|)),  b/pi ).
// Scan recurrence (revolutions): q = fma(u, A, b/pi + t2); u = v_sin(q),
// with u = (hr+hi)/sqrt2, q = psi/(2pi) + 1/8,
// t2 = fmodf(t*PHI, 2pi)*INV_PI + 0.125  (bit-identical to reference path).
// ---------------------------------------------------------------------------
__global__ __launch_bounds__(256) void transform_kernel(
    const float* __restrict__ emb, float2* __restrict__ embT)
{
    int e = blockIdx.x * 256 + threadIdx.x;   // [0, 32000*64)
    int v = e >> 6, d = e & 63;
    float w = emb[(v << 7) + d];
    float b = emb[(v << 7) + 64 + d];
    embT[e] = make_float2(SQ2_I2PI * __builtin_amdgcn_rcpf(1.0f + fabsf(w)),
                          b * INV_PI_F);
}

// ---------------------------------------------------------------------------
// Phase 1: producer/consumer scan.  grid = B (64 blocks), block = 320 threads
// (wave 0 = consumer, waves 1..4 = producers).  Producers gather tile t+1
// (A, C) pairs into an LDS double buffer while the consumer runs the serial
// chain on tile t.  Latency hiding is enforced by the double buffer +
// barrier, not compiler load scheduling (failed in rounds 2-3).
// ROUND-5 FIX vs round 4: all per-step arithmetic is bit-identical to the
// passing round-2/3 kernel (s_t2 LDS table with fmodf, same C sum order);
// round 4's incremental fract-stepped tau (~4e-4 rad/step off) was amplified
// ~1e3-1e5x by the recurrence -> absmax 3.05.  Never change scan arithmetic
// and schedule in the same round.
// ---------------------------------------------------------------------------
template<bool XF>
__global__ __launch_bounds__(PWAVES * 64 + 64, 1) void scan_fused(
    const int*    __restrict__ ids,
    const float*  __restrict__ embR,    // raw emb       (used when !XF)
    const float2* __restrict__ embT,    // transformed   (used when XF)
    float2*       __restrict__ xf)      // [b][d] final (hr,hi)
{
    __shared__ float  s_t2[S_LEN];                // 16 KB: tau/pi + 0.125
    __shared__ float2 sAC[2][TILE][D_SZ];         // 128 KB double buffer

    const int b    = blockIdx.x;
    const int tidx = threadIdx.x;
    const int wv   = tidx >> 6;        // 0 = consumer, 1..4 = producers
    const int lane = tidx & 63;        // = d

    const int* __restrict__ ids_b = ids + b * S_LEN;

    for (int i = tidx; i < S_LEN; i += (PWAVES + 1) * 64)
        s_t2[i] = fmodf((float)i * PHI_F, TWO_PI_F) * INV_PI_F + 0.125f;
    __syncthreads();

// producer: fill strip of tile TLE into buffer BUF
#define FILL(BUF, TLE) do {                                                  \
    const int t0_ = (TLE) * TILE + (wv - 1) * PSTEPS;                        \
    const int s0_ = (wv - 1) * PSTEPS;                                       \
    _Pragma("unroll")                                                        \
    for (int jj = 0; jj < PSTEPS; ++jj) {                                    \
        int   row_ = ids_b[t0_ + jj] << (XF ? 6 : 7);                        \
        float t2_  = s_t2[t0_ + jj];                                         \
        float A_, C_;                                                        \
        if constexpr (XF) {                                                  \
            float2 e_ = embT[row_ + lane];                                   \
            A_ = e_.x;                                                       \
            C_ = e_.y + t2_;                                                 \
        } else {                                                             \
            float w_  = embR[row_ + lane];                                   \
            float bb_ = embR[row_ + 64 + lane];                              \
            A_ = SQ2_I2PI * __builtin_amdgcn_rcpf(1.0f + fabsf(w_));         \
            C_ = fmaf(bb_, INV_PI_F, t2_);                                   \
        }                                                                    \
        sAC[BUF][s0_ + jj][lane] = make_float2(A_, C_);                      \
    }                                                                        \
} while (0)

// consumer: 16-step register groups, ping-pong so ds_read latency hides
// under the previous group's fma->v_sin chain
#define LOADG(R, BUF, G) do {                                                \
    _Pragma("unroll")                                                        \
    for (int j = 0; j < GRP; ++j) R[j] = sAC[BUF][(G) * GRP + j][lane];      \
} while (0)

#define COMPG(R) do {                                                        \
    _Pragma("unroll")                                                        \
    for (int j = 0; j < GRP; ++j) {                                          \
        q = fmaf(u, R[j].x, R[j].y);                                         \
        u = __builtin_amdgcn_sinf(q);                                        \
    }                                                                        \
} while (0)

#define CONSUME(BUF) do {                                                    \
    float2 rA[GRP], rB[GRP];                                                 \
    LOADG(rA, BUF, 0);                                                       \
    LOADG(rB, BUF, 1); COMPG(rA);                                            \
    LOADG(rA, BUF, 2); COMPG(rB);                                            \
    LOADG(rB, BUF, 3); COMPG(rA);                                            \
    LOADG(rA, BUF, 4); COMPG(rB);                                            \
    LOADG(rB, BUF, 5); COMPG(rA);                                            \
    LOADG(rA, BUF, 6); COMPG(rB);                                            \
    LOADG(rB, BUF, 7); COMPG(rA);                                            \
    COMPG(rB);                                                               \
} while (0)

    float u = 0.0f, q = 0.0f;

    if (wv > 0) FILL(0, 0);
    __syncthreads();

    for (int t = 0; t < NT; ++t) {
        const int cur = t & 1;
        if (wv > 0) {
            if (t + 1 < NT) FILL(cur ^ 1, t + 1);
        } else {
            CONSUME(cur);
        }
        __syncthreads();
    }

    if (wv == 0) {
        float pr = q - 0.125f;    // = psi_final / (2*pi), revolutions
        xf[b * 64 + lane] = make_float2(__builtin_amdgcn_cosf(pr),
                                        __builtin_amdgcn_sinf(pr));
    }

#undef FILL
#undef LOADG
#undef COMPG
#undef CONSUME
}

// ---------------------------------------------------------------------------
// Phase 2: the two resonant layers at t_last = (S-1)*phi.
// grid = B (64 blocks), block = N (128 threads).
// ---------------------------------------------------------------------------
__global__ __launch_bounds__(128) void layers_kernel(
    const float2* __restrict__ xf,       // [b][d]
    const float*  __restrict__ win_r,    // [L][D][N]
    const float*  __restrict__ win_i,
    const float*  __restrict__ wout_r,   // [L][N][D]
    const float*  __restrict__ wout_i,
    const float*  __restrict__ lw,       // [L][N]
    const float*  __restrict__ lb,
    float2*       __restrict__ xft)      // [d][b] for the projection kernel
{
    const int b = blockIdx.x;
    const int n = threadIdx.x;

    __shared__ float s_xr[D_SZ], s_xi[D_SZ];
    __shared__ float s_vr[N_SZ], s_vi[N_SZ];

    if (n < D_SZ) {
        float2 v = xf[b * D_SZ + n];
        s_xr[n] = v.x;
        s_xi[n] = v.y;
    }
    __syncthreads();

    const float t_last = (float)(4095.0 * 1.618033988749895);
    const float t_wrap = fmodf(t_last, TWO_PI_F);

    for (int l = 0; l < L_SZ; ++l) {
        float ur = 0.0f, ui = 0.0f;
        const float* wr = win_r + l * D_SZ * N_SZ;
        const float* wi = win_i + l * D_SZ * N_SZ;
        for (int dd = 0; dd < D_SZ; ++dd) {
            float xr = s_xr[dd], xi = s_xi[dd];
            float ar = wr[dd * N_SZ + n], ai = wi[dd * N_SZ + n];
            ur = fmaf(xr, ar, fmaf(-xi, ai, ur));
            ui = fmaf(xr, ai, fmaf( xi, ar, ui));
        }
        float lam = 1.0f + fabsf(lw[l * N_SZ + n]);
        float th  = t_wrap / lam + lb[l * N_SZ + n];
        float sn  = sinf(th), cs = cosf(th);
        float vr  = ur * cs - ui * sn;
        float vi  = ur * sn + ui * cs;
        vr = vr / (1.0f + expf(-vr));
        vi = vi / (1.0f + expf(-vi));
        s_vr[n] = vr;
        s_vi[n] = vi;
        __syncthreads();

        float yr = 0.0f, yi = 0.0f;
        if (n < D_SZ) {
            const float* orp = wout_r + l * N_SZ * D_SZ;
            const float* oip = wout_i + l * N_SZ * D_SZ;
            for (int j = 0; j < N_SZ; ++j) {
                float vr2 = s_vr[j], vi2 = s_vi[j];
                float br = orp[j * D_SZ + n], bi = oip[j * D_SZ + n];
                yr = fmaf(vr2, br, fmaf(-vi2, bi, yr));
                yi = fmaf(vr2, bi, fmaf( vi2, br, yi));
            }
        }
        __syncthreads();
        if (n < D_SZ) {
            s_xr[n] = yr;
            s_xi[n] = yi;
        }
        __syncthreads();
    }

    if (n < D_SZ) {
        xft[n * B_SZ + b] = make_float2(s_xr[n], s_xi[n]);
    }
}

// ---------------------------------------------------------------------------
// Phase 3: out[b][v] = xr[b]@(wr+wi)[:,v] + xi[b]@(wr-wi)[:,v].
// ---------------------------------------------------------------------------
#define VCH 16
__global__ __launch_bounds__(64) void proj_kernel(
    const float2* __restrict__ xft,    // [d][b]
    const float*  __restrict__ owr,    // [D][NSIG]
    const float*  __restrict__ owi,
    float*        __restrict__ out)    // [B][NSIG]
{
    const int v0   = blockIdx.x * VCH;
    const int lane = threadIdx.x;      // = b

    float acc[VCH];
    #pragma unroll
    for (int k = 0; k < VCH; ++k) acc[k] = 0.0f;

    for (int dd = 0; dd < D_SZ; ++dd) {
        float2 x = xft[dd * B_SZ + lane];
        #pragma unroll
        for (int k = 0; k < VCH; ++k) {
            float a = owr[dd * NSIG + v0 + k];
            float c = owi[dd * NSIG + v0 + k];
            acc[k] = fmaf(x.x, a + c, fmaf(x.y, a - c, acc[k]));
        }
    }

    float4* o4 = (float4*)(out + (size_t)lane * NSIG + v0);
    #pragma unroll
    for (int k = 0; k < VCH / 4; ++k) {
        o4[k] = make_float4(acc[4 * k], acc[4 * k + 1],
                            acc[4 * k + 2], acc[4 * k + 3]);
    }
}

// ---------------------------------------------------------------------------
extern "C" void kernel_launch(void* const* d_in, const int* in_sizes, int n_in,
                              void* d_out, int out_size, void* d_ws, size_t ws_size,
                              hipStream_t stream)
{
    const int*   ids    = (const int*)  d_in[0];
    const float* emb    = (const float*)d_in[1];
    const float* win_r  = (const float*)d_in[2];
    const float* win_i  = (const float*)d_in[3];
    const float* wout_r = (const float*)d_in[4];
    const float* wout_i = (const float*)d_in[5];
    const float* lw     = (const float*)d_in[6];
    const float* lb     = (const float*)d_in[7];
    const float* owr    = (const float*)d_in[8];
    const float* owi    = (const float*)d_in[9];
    float*       out    = (float*)d_out;

    float2* xf   = (float2*)d_ws;                        // 32 KB
    float2* xft  = (float2*)((char*)d_ws + 32 * 1024);   // 32 KB
    float2* embT = (float2*)((char*)d_ws + 64 * 1024);   // 16.4 MB

    const size_t need = 64 * 1024 + (size_t)NSIG * 64 * sizeof(float2);
    const int nthreads = (PWAVES + 1) * 64;
    if (ws_size >= need) {
        transform_kernel<<<NSIG * 64 / 256, 256, 0, stream>>>(emb, embT);
        scan_fused<true><<<B_SZ, nthreads, 0, stream>>>(ids, emb, embT, xf);
    } else {
        scan_fused<false><<<B_SZ, nthreads, 0, stream>>>(ids, emb,
                                                         (const float2*)emb, xf);
    }
    layers_kernel<<<B_SZ, 128, 0, stream>>>(xf, win_r, win_i, wout_r, wout_i,
                                            lw, lb, xft);
    proj_kernel<<<NSIG / VCH, 64, 0, stream>>>(xft, owr, owi, out);
}